// Round 1
// baseline (68.420 us; speedup 1.0000x reference)
//
#include <hip/hip_runtime.h>
#include <hip/hip_fp16.h>
#include <stdint.h>

#define BATCH 128
#define CIN   64
#define NFLOW 16
#define COUT  256
#define HH    20
#define WW    20
#define NPIX  400
#define KTOT  1024
#define PT    80          // pixel tile
#define NPT   5           // tiles per batch
#define NTH   256         // 4 waves
#define FLS   72          // f16 per fl row = 144 B (odd 16B stride -> quad-cycling)

typedef __attribute__((ext_vector_type(8))) short sh8;   // MFMA A/B frag (8 f16)
typedef __attribute__((ext_vector_type(4))) float f4;    // MFMA C/D frag

// ---- prep: W fp32 [256][1024] -> f16 MFMA-frag layout over permuted k' ----
// k' = kc*64 + fi*8 + ci ; kc = fb*8 + cb ; f = fb*8+fi, c = cb*8+ci, k = c*16+f.
// Frag layout: Wf[((kc16*16 + mf)*64 + h*16 + lr)*8 + j], k' = kc16*32 + h*8 + j,
// row m = mf*16 + lr.
__global__ void prep_w(const float* __restrict__ wg, __half* __restrict__ Wf) {
    int gid = blockIdx.x * 256 + threadIdx.x;   // [0, 32768)
    int j8  = gid & 127;          // k'-octet 0..127
    int row = gid >> 7;           // 0..255
    int kc16 = j8 >> 2;
    int h    = j8 & 3;
    __half* dst = Wf + ((size_t)(kc16 * 16 + (row >> 4)) * 64 + h * 16 + (row & 15)) * 8;
    #pragma unroll
    for (int j = 0; j < 8; ++j) {
        int kp = j8 * 8 + j;                  // k' in [0,1024)
        int kc = kp >> 6;
        int l  = kp & 63;
        int f  = (kc >> 3) * 8 + (l >> 3);
        int c  = (kc & 7) * 8 + (l & 7);
        dst[j] = __float2half(wg[(size_t)row * KTOT + c * NFLOW + f]);
    }
}

__global__ __launch_bounds__(NTH, 3) void flow_main(
    const float* __restrict__ xg, const __half* __restrict__ Wf,
    const float* __restrict__ flowg, const float* __restrict__ biasg,
    float* __restrict__ outg)
{
    // xc: current+next chunk's 8 channels, [pix*8 + ci] f16 (16 B/pixel cell)
    __shared__ __align__(16) __half xc[2][NPIX * 8];      // 12800 B
    __shared__ __align__(16) __half fl[2][PT * FLS];      // 23040 B  (total 35840 B)

    const int bid0 = blockIdx.x;
    const int bid  = (bid0 & 7) * (BATCH * NPT / 8) + (bid0 >> 3);  // XCD swizzle
    const int b  = bid / NPT;
    const int pt = bid - b * NPT;
    const int p0 = pt * PT;

    const int tid  = threadIdx.x;
    const int wv   = tid >> 6;
    const int lane = tid & 63;
    const int lr   = lane & 15;
    const int lk   = (lane >> 4) * 8;

    const float* xb = xg + (size_t)b * (CIN * NPIX);

    // ---- bilinear warp tables: per (fi,p) group of the active flow-block ----
    __half2 w2_[3][4];
    int     pb_[3][4];     // corner cell byte offsets in xc (pr*16)
    int     fo_[3];        // fl byte offset = p*144 + fi*16

    auto build_tables = [&](int fb) {
        #pragma unroll
        for (int gi = 0; gi < 3; ++gi) {
            int g = tid + gi * NTH;            // g = fi*80 + p  (p contiguous per wave)
            if (g < PT * 8) {
                int fi = g / PT;
                int p  = g - fi * PT;
                int f  = fb * 8 + fi;
                int gp = p0 + p;
                int i = gp / WW;
                int j = gp - i * WW;
                float fx = flowg[((f * HH + i) * WW + j) * 2 + 0];
                float fy = flowg[((f * HH + i) * WW + j) * 2 + 1];
                float ax = (float)i + fx;
                float ay = (float)j + fy;
                float bxf = floorf(ax), byf = floorf(ay);
                float s = ax - bxf, t = ay - byf;
                int ibx = (int)bxf, iby = (int)byf;
                float w00 = (1.f - s) * (1.f - t);
                float w01 = s * (1.f - t);
                float w10 = s * (1.f - t);        // replicate reference's weight bug
                float w11 = s * t;
                int cx0 = min(max(ibx, 0), HH);
                int cx1 = min(max(ibx + 1, 0), HH);
                int cy0 = min(max(iby, 0), WW);
                int cy1 = min(max(iby + 1, 0), WW);
                int v0 = (cx0 < HH) & (cy0 < WW);
                int v1 = (cx1 < HH) & (cy0 < WW);
                int v2 = (cx0 < HH) & (cy1 < WW);
                int v3 = (cx1 < HH) & (cy1 < WW);
                w2_[gi][0] = __half2half2(__float2half(v0 ? w00 : 0.f));
                w2_[gi][1] = __half2half2(__float2half(v1 ? w01 : 0.f));
                w2_[gi][2] = __half2half2(__float2half(v2 ? w10 : 0.f));
                w2_[gi][3] = __half2half2(__float2half(v3 ? w11 : 0.f));
                pb_[gi][0] = (v0 ? (cx0 * WW + cy0) : 0) * 16;
                pb_[gi][1] = (v1 ? (cx1 * WW + cy0) : 0) * 16;
                pb_[gi][2] = (v2 ? (cx0 * WW + cy1) : 0) * 16;
                pb_[gi][3] = (v3 ? (cx1 * WW + cy1) : 0) * 16;
                fo_[gi] = p * (FLS * 2) + fi * 16;
            }
        }
    };

    // ---- prologue: stage chunk 0 (cb=0) into xc[0] ----
    {
        #pragma unroll
        for (int it = 0; it < 7; ++it) {
            int idx = it * NTH + tid;          // 1600 = 400 pix x 4 ch-pairs
            if (idx < 1600) {
                int pix = idx >> 2, q = idx & 3;
                float v0 = xb[(2 * q)     * NPIX + pix];
                float v1 = xb[(2 * q + 1) * NPIX + pix];
                __half2 h = __floats2half2_rn(v0, v1);
                *(uint32_t*)&xc[0][pix * 8 + 2 * q] = __builtin_bit_cast(uint32_t, h);
            }
        }
    }
    build_tables(0);
    __syncthreads();   // xc[0] staged, tables ready

    f4 acc[4][5] = {};

    for (int kc = 0; kc < 16; ++kc) {          // chunk = (fb = kc>>3, cb = kc&7)
        if (kc == 8) build_tables(1);

        // ---- issue next chunk's x loads (L2-resident), written after fill ----
        float rv0[7], rv1[7];
        const int ncb = (kc + 1) & 7;
        if (kc < 15) {
            #pragma unroll
            for (int it = 0; it < 7; ++it) {
                int idx = it * NTH + tid;
                if (idx < 1600) {
                    int pix = idx >> 2, q = idx & 3;
                    rv0[it] = xb[(ncb * 8 + 2 * q)     * NPIX + pix];
                    rv1[it] = xb[(ncb * 8 + 2 * q + 1) * NPIX + pix];
                }
            }
        }

        // ---- fill fl[kc&1]: per (fi,p) group, 4 corner b128 gathers + hfma2 ----
        {
            const char* xcb = (const char*)xc[kc & 1];
            char* flb = (char*)fl[kc & 1];
            #pragma unroll
            for (int gi = 0; gi < 3; ++gi) {
                if (tid + gi * NTH < PT * 8) {
                    __half2 s0 = __builtin_bit_cast(__half2, 0u);
                    __half2 s1 = s0, s2 = s0, s3 = s0;
                    #pragma unroll
                    for (int q = 0; q < 4; ++q) {
                        const uint4 d = *(const uint4*)(xcb + pb_[gi][q]);
                        __half2 wq = w2_[gi][q];
                        s0 = __hfma2(wq, __builtin_bit_cast(__half2, d.x), s0);
                        s1 = __hfma2(wq, __builtin_bit_cast(__half2, d.y), s1);
                        s2 = __hfma2(wq, __builtin_bit_cast(__half2, d.z), s2);
                        s3 = __hfma2(wq, __builtin_bit_cast(__half2, d.w), s3);
                    }
                    uint4 pk;
                    pk.x = __builtin_bit_cast(uint32_t, s0);
                    pk.y = __builtin_bit_cast(uint32_t, s1);
                    pk.z = __builtin_bit_cast(uint32_t, s2);
                    pk.w = __builtin_bit_cast(uint32_t, s3);
                    *(uint4*)(flb + fo_[gi]) = pk;      // 16B aligned, quad-cycling
                }
            }
        }

        // ---- write staged x into xc[(kc+1)&1] (dw-contiguous, conflict-free) ----
        if (kc < 15) {
            __half* xcn = xc[(kc + 1) & 1];
            #pragma unroll
            for (int it = 0; it < 7; ++it) {
                int idx = it * NTH + tid;
                if (idx < 1600) {
                    int pix = idx >> 2, q = idx & 3;
                    __half2 h = __floats2half2_rn(rv0[it], rv1[it]);
                    *(uint32_t*)&xcn[pix * 8 + 2 * q] = __builtin_bit_cast(uint32_t, h);
                }
            }
        }

        // ---- A-frags: 4 M-frags x 2 k-halves, direct global (L2) ----
        const sh8* wfp = (const sh8*)Wf + (size_t)(32 * kc + 4 * wv) * 64 + lane;
        sh8 a0_0 = wfp[0],    a0_1 = wfp[64],   a0_2 = wfp[128],  a0_3 = wfp[192];
        sh8 a1_0 = wfp[1024], a1_1 = wfp[1088], a1_2 = wfp[1152], a1_3 = wfp[1216];

        __syncthreads();   // fl[kc&1] + xc[(kc+1)&1] ready (sole barrier per chunk)

        // ---- MFMA: 40 x 16x16x32_f16 per wave ----
        const __half* flr = fl[kc & 1];
        __builtin_amdgcn_s_setprio(1);
        #pragma unroll
        for (int nf = 0; nf < 5; ++nf) {
            sh8 b0 = *(const sh8*)&flr[(nf * 16 + lr) * FLS + lk];
            acc[0][nf] = __builtin_amdgcn_mfma_f32_16x16x32_f16(a0_0, b0, acc[0][nf], 0, 0, 0);
            acc[1][nf] = __builtin_amdgcn_mfma_f32_16x16x32_f16(a0_1, b0, acc[1][nf], 0, 0, 0);
            acc[2][nf] = __builtin_amdgcn_mfma_f32_16x16x32_f16(a0_2, b0, acc[2][nf], 0, 0, 0);
            acc[3][nf] = __builtin_amdgcn_mfma_f32_16x16x32_f16(a0_3, b0, acc[3][nf], 0, 0, 0);
            sh8 b1 = *(const sh8*)&flr[(nf * 16 + lr) * FLS + 32 + lk];
            acc[0][nf] = __builtin_amdgcn_mfma_f32_16x16x32_f16(a1_0, b1, acc[0][nf], 0, 0, 0);
            acc[1][nf] = __builtin_amdgcn_mfma_f32_16x16x32_f16(a1_1, b1, acc[1][nf], 0, 0, 0);
            acc[2][nf] = __builtin_amdgcn_mfma_f32_16x16x32_f16(a1_2, b1, acc[2][nf], 0, 0, 0);
            acc[3][nf] = __builtin_amdgcn_mfma_f32_16x16x32_f16(a1_3, b1, acc[3][nf], 0, 0, 0);
        }
        __builtin_amdgcn_s_setprio(0);
        // no trailing barrier: next fill/stage target the other buffers
    }

    // ---- epilogue: bias + fp32 store ----
    float* ob = outg + (size_t)b * (COUT * NPIX) + p0;
    #pragma unroll
    for (int mi = 0; mi < 4; ++mi) {
        #pragma unroll
        for (int r = 0; r < 4; ++r) {
            int m = wv * 64 + mi * 16 + (lane >> 4) * 4 + r;
            float bs = biasg[m];
            #pragma unroll
            for (int nf = 0; nf < 5; ++nf)
                ob[(size_t)m * NPIX + nf * 16 + lr] = acc[mi][nf][r] + bs;
        }
    }
}

extern "C" void kernel_launch(void* const* d_in, const int* in_sizes, int n_in,
                              void* d_out, int out_size, void* d_ws, size_t ws_size,
                              hipStream_t stream) {
    const float* x    = (const float*)d_in[0];
    const float* flow = (const float*)d_in[1];
    const float* comb = (const float*)d_in[2];
    const float* bias = (const float*)d_in[3];
    float* out = (float*)d_out;

    __half* Wf = (__half*)d_ws;   // 512 KB frag-layout f16 W

    prep_w<<<dim3(128), dim3(256), 0, stream>>>(comb, Wf);
    flow_main<<<dim3(BATCH * NPT), dim3(NTH), 0, stream>>>(x, Wf, flow, bias, out);
}

// Round 3
// 56.994 us; speedup vs baseline: 1.2005x; 1.2005x over previous
//
#include <hip/hip_runtime.h>
#include <hip/hip_fp16.h>
#include <stdint.h>

#define BATCH 128
#define CIN   64
#define NFLOW 16
#define COUT  256
#define HH    20
#define WW    20
#define NPIX  400
#define KTOT  1024
#define PT    80          // pixel tile
#define NPT   5           // tiles per batch
#define NTH   512         // 8 waves = 4 M-groups x 2 N-groups
#define FLS   72          // f16 per fl row = 144 B

typedef __attribute__((ext_vector_type(8))) short sh8;   // MFMA A/B frag (8 f16)
typedef __attribute__((ext_vector_type(4))) float f4;    // MFMA C/D frag

// ---- prep: W fp32 [256][1024] -> f16 MFMA-frag layout over permuted k' ----
// k' = kc*64 + fi*8 + ci ; kc = fb*8 + cb ; f = fb*8+fi, c = cb*8+ci, k = c*16+f.
// Frag layout: Wf[((kc16*16 + mf)*64 + h*16 + lr)*8 + j], k' = kc16*32 + h*8 + j,
// row m = mf*16 + lr.
__global__ void prep_w(const float* __restrict__ wg, __half* __restrict__ Wf) {
    int gid = blockIdx.x * 256 + threadIdx.x;   // [0, 32768)
    int j8  = gid & 127;          // k'-octet 0..127
    int row = gid >> 7;           // 0..255
    int kc16 = j8 >> 2;
    int h    = j8 & 3;
    __half* dst = Wf + ((size_t)(kc16 * 16 + (row >> 4)) * 64 + h * 16 + (row & 15)) * 8;
    #pragma unroll
    for (int j = 0; j < 8; ++j) {
        int kp = j8 * 8 + j;                  // k' in [0,1024)
        int kc = kp >> 6;
        int l  = kp & 63;
        int f  = (kc >> 3) * 8 + (l >> 3);
        int c  = (kc & 7) * 8 + (l & 7);
        dst[j] = __float2half(wg[(size_t)row * KTOT + c * NFLOW + f]);
    }
}

__global__ __launch_bounds__(NTH, 4) void flow_main(
    const float* __restrict__ xg, const __half* __restrict__ Wf,
    const float* __restrict__ flowg, const float* __restrict__ biasg,
    float* __restrict__ outg)
{
    // xb: whole image, cell layout xb[cb*3200 + pix*8 + ci] (16 B / pixel-cell)
    __shared__ __align__(16) __half xb[CIN * NPIX];       // 51200 B
    __shared__ __align__(16) __half fl[2][PT * FLS];      // 23040 B   (total 74240 B)

    const int bid0 = blockIdx.x;
    const int bid  = (bid0 & 7) * (BATCH * NPT / 8) + (bid0 >> 3);  // XCD swizzle
    const int b  = bid / NPT;
    const int pt = bid - b * NPT;
    const int p0 = pt * PT;

    const int tid  = threadIdx.x;
    const int wv   = tid >> 6;
    const int wm   = wv & 3;          // M group: rows [wm*64, wm*64+64)
    const int wn   = wv >> 2;         // N group: 0 -> nf {0,1}, 1 -> nf {2,3,4}
    const int lane = tid & 63;
    const int lr   = lane & 15;
    const int lk   = (lane >> 4) * 8;

    const float* xsrc = xg + (size_t)b * (CIN * NPIX);

    // ---- stage x once: f32 global -> f16 cells (b128 writes, stride-16B) ----
    #pragma unroll
    for (int it = 0; it < 7; ++it) {
        int idx = it * NTH + tid;              // cell id in [0, 3200)
        if (idx < 3200) {
            int cb  = idx / NPIX;
            int pix = idx - cb * NPIX;
            const float* s = xsrc + (size_t)(cb * 8) * NPIX + pix;
            __half2 h0 = __floats2half2_rn(s[0 * NPIX], s[1 * NPIX]);
            __half2 h1 = __floats2half2_rn(s[2 * NPIX], s[3 * NPIX]);
            __half2 h2 = __floats2half2_rn(s[4 * NPIX], s[5 * NPIX]);
            __half2 h3 = __floats2half2_rn(s[6 * NPIX], s[7 * NPIX]);
            uint4 pk;
            pk.x = __builtin_bit_cast(uint32_t, h0);
            pk.y = __builtin_bit_cast(uint32_t, h1);
            pk.z = __builtin_bit_cast(uint32_t, h2);
            pk.w = __builtin_bit_cast(uint32_t, h3);
            *(uint4*)&xb[(size_t)idx * 8] = pk;
        }
    }

    // ---- bilinear warp tables: 640 (fi,p) groups over 512 threads ----
    __half2 w2_[2][4];
    int     pb_[2][4];     // corner cell byte offset within cb-plane (pr*16)
    int     fo_[2];        // fl byte offset = p*144 + fi*16

    auto build_tables = [&](int fb) {
        #pragma unroll
        for (int gi = 0; gi < 2; ++gi) {
            int g = tid + gi * NTH;            // g = fi*80 + p (p contiguous per wave)
            if (g < PT * 8) {
                int fi = g / PT;
                int p  = g - fi * PT;
                int f  = fb * 8 + fi;
                int gp = p0 + p;
                int i = gp / WW;
                int j = gp - i * WW;
                float fx = flowg[((f * HH + i) * WW + j) * 2 + 0];
                float fy = flowg[((f * HH + i) * WW + j) * 2 + 1];
                float ax = (float)i + fx;
                float ay = (float)j + fy;
                float bxf = floorf(ax), byf = floorf(ay);
                float s = ax - bxf, t = ay - byf;
                int ibx = (int)bxf, iby = (int)byf;
                float w00 = (1.f - s) * (1.f - t);
                float w01 = s * (1.f - t);
                float w10 = s * (1.f - t);        // replicate reference's weight bug
                float w11 = s * t;
                int cx0 = min(max(ibx, 0), HH);
                int cx1 = min(max(ibx + 1, 0), HH);
                int cy0 = min(max(iby, 0), WW);
                int cy1 = min(max(iby + 1, 0), WW);
                int v0 = (cx0 < HH) & (cy0 < WW);
                int v1 = (cx1 < HH) & (cy0 < WW);
                int v2 = (cx0 < HH) & (cy1 < WW);
                int v3 = (cx1 < HH) & (cy1 < WW);
                w2_[gi][0] = __half2half2(__float2half(v0 ? w00 : 0.f));
                w2_[gi][1] = __half2half2(__float2half(v1 ? w01 : 0.f));
                w2_[gi][2] = __half2half2(__float2half(v2 ? w10 : 0.f));
                w2_[gi][3] = __half2half2(__float2half(v3 ? w11 : 0.f));
                pb_[gi][0] = (v0 ? (cx0 * WW + cy0) : 0) * 16;
                pb_[gi][1] = (v1 ? (cx1 * WW + cy0) : 0) * 16;
                pb_[gi][2] = (v2 ? (cx0 * WW + cy1) : 0) * 16;
                pb_[gi][3] = (v3 ? (cx1 * WW + cy1) : 0) * 16;
                fo_[gi] = p * (FLS * 2) + fi * 16;
            }
        }
    };

    build_tables(0);
    __syncthreads();   // xb staged

    f4 acc[4][3] = {};   // [mi][ni]; wn==0 uses ni 0..1, wn==1 uses ni 0..2

    for (int kc = 0; kc < 16; ++kc) {          // chunk = (fb = kc>>3, cb = kc&7)
        const int cb = kc & 7;
        if (kc == 8) build_tables(1);

        // ---- A-frags: 4 M-frags x 2 k-halves, direct global (L2-resident) ----
        const sh8* wfp = (const sh8*)Wf + (size_t)(32 * kc + 4 * wm) * 64 + lane;
        sh8 a0_0 = wfp[0],    a0_1 = wfp[64],   a0_2 = wfp[128],  a0_3 = wfp[192];
        sh8 a1_0 = wfp[1024], a1_1 = wfp[1088], a1_2 = wfp[1152], a1_3 = wfp[1216];

        // ---- fill fl[kc&1]: per (fi,p) group, 4 corner b128 gathers + hfma2 ----
        {
            const char* xcb = (const char*)xb + cb * 6400;
            char* flb = (char*)fl[kc & 1];
            #pragma unroll
            for (int gi = 0; gi < 2; ++gi) {
                if (tid + gi * NTH < PT * 8) {
                    __half2 s0 = __builtin_bit_cast(__half2, 0u);
                    __half2 s1 = s0, s2 = s0, s3 = s0;
                    #pragma unroll
                    for (int q = 0; q < 4; ++q) {
                        const uint4 d = *(const uint4*)(xcb + pb_[gi][q]);
                        __half2 wq = w2_[gi][q];
                        s0 = __hfma2(wq, __builtin_bit_cast(__half2, d.x), s0);
                        s1 = __hfma2(wq, __builtin_bit_cast(__half2, d.y), s1);
                        s2 = __hfma2(wq, __builtin_bit_cast(__half2, d.z), s2);
                        s3 = __hfma2(wq, __builtin_bit_cast(__half2, d.w), s3);
                    }
                    uint4 pk;
                    pk.x = __builtin_bit_cast(uint32_t, s0);
                    pk.y = __builtin_bit_cast(uint32_t, s1);
                    pk.z = __builtin_bit_cast(uint32_t, s2);
                    pk.w = __builtin_bit_cast(uint32_t, s3);
                    *(uint4*)(flb + fo_[gi]) = pk;
                }
            }
        }

        __syncthreads();   // fl[kc&1] ready (sole barrier; dbuf allows skew)

        // ---- MFMA: wn==0 -> 16, wn==1 -> 24 per wave (160/block/chunk) ----
        const __half* flr = fl[kc & 1];
        __builtin_amdgcn_s_setprio(1);
        if (wn == 0) {
            #pragma unroll
            for (int ni = 0; ni < 2; ++ni) {
                sh8 b0 = *(const sh8*)&flr[(ni * 16 + lr) * FLS + lk];
                acc[0][ni] = __builtin_amdgcn_mfma_f32_16x16x32_f16(a0_0, b0, acc[0][ni], 0, 0, 0);
                acc[1][ni] = __builtin_amdgcn_mfma_f32_16x16x32_f16(a0_1, b0, acc[1][ni], 0, 0, 0);
                acc[2][ni] = __builtin_amdgcn_mfma_f32_16x16x32_f16(a0_2, b0, acc[2][ni], 0, 0, 0);
                acc[3][ni] = __builtin_amdgcn_mfma_f32_16x16x32_f16(a0_3, b0, acc[3][ni], 0, 0, 0);
                sh8 b1 = *(const sh8*)&flr[(ni * 16 + lr) * FLS + 32 + lk];
                acc[0][ni] = __builtin_amdgcn_mfma_f32_16x16x32_f16(a1_0, b1, acc[0][ni], 0, 0, 0);
                acc[1][ni] = __builtin_amdgcn_mfma_f32_16x16x32_f16(a1_1, b1, acc[1][ni], 0, 0, 0);
                acc[2][ni] = __builtin_amdgcn_mfma_f32_16x16x32_f16(a1_2, b1, acc[2][ni], 0, 0, 0);
                acc[3][ni] = __builtin_amdgcn_mfma_f32_16x16x32_f16(a1_3, b1, acc[3][ni], 0, 0, 0);
            }
        } else {
            #pragma unroll
            for (int ni = 0; ni < 3; ++ni) {
                sh8 b0 = *(const sh8*)&flr[((ni + 2) * 16 + lr) * FLS + lk];
                acc[0][ni] = __builtin_amdgcn_mfma_f32_16x16x32_f16(a0_0, b0, acc[0][ni], 0, 0, 0);
                acc[1][ni] = __builtin_amdgcn_mfma_f32_16x16x32_f16(a0_1, b0, acc[1][ni], 0, 0, 0);
                acc[2][ni] = __builtin_amdgcn_mfma_f32_16x16x32_f16(a0_2, b0, acc[2][ni], 0, 0, 0);
                acc[3][ni] = __builtin_amdgcn_mfma_f32_16x16x32_f16(a0_3, b0, acc[3][ni], 0, 0, 0);
                sh8 b1 = *(const sh8*)&flr[((ni + 2) * 16 + lr) * FLS + 32 + lk];
                acc[0][ni] = __builtin_amdgcn_mfma_f32_16x16x32_f16(a1_0, b1, acc[0][ni], 0, 0, 0);
                acc[1][ni] = __builtin_amdgcn_mfma_f32_16x16x32_f16(a1_1, b1, acc[1][ni], 0, 0, 0);
                acc[2][ni] = __builtin_amdgcn_mfma_f32_16x16x32_f16(a1_2, b1, acc[2][ni], 0, 0, 0);
                acc[3][ni] = __builtin_amdgcn_mfma_f32_16x16x32_f16(a1_3, b1, acc[3][ni], 0, 0, 0);
            }
        }
        __builtin_amdgcn_s_setprio(0);
        // no trailing barrier: next fill targets the other buffer
    }

    // ---- epilogue: bias + fp32 store (N groups write disjoint columns) ----
    float* ob = outg + (size_t)b * (COUT * NPIX) + p0;
    #pragma unroll
    for (int mi = 0; mi < 4; ++mi) {
        #pragma unroll
        for (int r = 0; r < 4; ++r) {
            int m = wm * 64 + mi * 16 + (lane >> 4) * 4 + r;
            float bs = biasg[m];
            if (wn == 0) {
                #pragma unroll
                for (int ni = 0; ni < 2; ++ni)
                    ob[(size_t)m * NPIX + ni * 16 + lr] = acc[mi][ni][r] + bs;
            } else {
                #pragma unroll
                for (int ni = 0; ni < 3; ++ni)
                    ob[(size_t)m * NPIX + (ni + 2) * 16 + lr] = acc[mi][ni][r] + bs;
            }
        }
    }
}

extern "C" void kernel_launch(void* const* d_in, const int* in_sizes, int n_in,
                              void* d_out, int out_size, void* d_ws, size_t ws_size,
                              hipStream_t stream) {
    const float* x    = (const float*)d_in[0];
    const float* flow = (const float*)d_in[1];
    const float* comb = (const float*)d_in[2];
    const float* bias = (const float*)d_in[3];
    float* out = (float*)d_out;

    __half* Wf = (__half*)d_ws;   // 512 KB frag-layout f16 W

    prep_w<<<dim3(128), dim3(256), 0, stream>>>(comb, Wf);
    flow_main<<<dim3(BATCH * NPT), dim3(NTH), 0, stream>>>(x, Wf, flow, bias, out);
}

// Round 4
// 55.625 us; speedup vs baseline: 1.2300x; 1.0246x over previous
//
#include <hip/hip_runtime.h>
#include <hip/hip_fp16.h>
#include <stdint.h>

#define BATCH 128
#define CIN   64
#define NFLOW 16
#define COUT  256
#define HH    20
#define WW    20
#define NPIX  400
#define KTOT  1024
#define PT    80          // pixel tile
#define NPT   5           // tiles per batch
#define NTH   512         // 8 waves, each owns 32 out-rows x all 5 N-frags
#define FLS   72          // f16 per fl row = 144 B

typedef __attribute__((ext_vector_type(8))) short sh8;   // MFMA A/B frag (8 f16)
typedef __attribute__((ext_vector_type(4))) float f4;    // MFMA C/D frag

// ---- prep: W fp32 [256][1024] -> f16 MFMA-frag layout over permuted k' ----
// k' = kc*64 + fi*8 + ci ; kc = fb*8 + cb ; f = fb*8+fi, c = cb*8+ci, k = c*16+f.
// Frag layout: Wf[((kc16*16 + mf)*64 + h*16 + lr)*8 + j], k' = kc16*32 + h*8 + j,
// row m = mf*16 + lr.
__global__ void prep_w(const float* __restrict__ wg, __half* __restrict__ Wf) {
    int gid = blockIdx.x * 256 + threadIdx.x;   // [0, 32768)
    int j8  = gid & 127;          // k'-octet 0..127
    int row = gid >> 7;           // 0..255
    int kc16 = j8 >> 2;
    int h    = j8 & 3;
    __half* dst = Wf + ((size_t)(kc16 * 16 + (row >> 4)) * 64 + h * 16 + (row & 15)) * 8;
    #pragma unroll
    for (int j = 0; j < 8; ++j) {
        int kp = j8 * 8 + j;                  // k' in [0,1024)
        int kc = kp >> 6;
        int l  = kp & 63;
        int f  = (kc >> 3) * 8 + (l >> 3);
        int c  = (kc & 7) * 8 + (l & 7);
        dst[j] = __float2half(wg[(size_t)row * KTOT + c * NFLOW + f]);
    }
}

__global__ __launch_bounds__(NTH, 4) void flow_main(
    const float* __restrict__ xg, const __half* __restrict__ Wf,
    const float* __restrict__ flowg, const float* __restrict__ biasg,
    float* __restrict__ outg)
{
    // xb: whole image, cell layout xb[cb*3200 + pix*8 + ci] (16 B / pixel-cell)
    __shared__ __align__(16) __half xb[CIN * NPIX];       // 51200 B
    __shared__ __align__(16) __half fl[2][PT * FLS];      // 23040 B   (total 74240 B)

    const int bid0 = blockIdx.x;
    const int bid  = (bid0 & 7) * (BATCH * NPT / 8) + (bid0 >> 3);  // XCD swizzle
    const int b  = bid / NPT;
    const int pt = bid - b * NPT;
    const int p0 = pt * PT;

    const int tid  = threadIdx.x;
    const int wv   = tid >> 6;        // wave owns out-rows [wv*32, wv*32+32), flow fi=wv
    const int lane = tid & 63;
    const int lr   = lane & 15;
    const int lk   = (lane >> 4) * 8;

    const float* xsrc = xg + (size_t)b * (CIN * NPIX);

    // ---- stage x once: f32 global -> f16 cells (b128 writes, stride-16B) ----
    #pragma unroll
    for (int it = 0; it < 7; ++it) {
        int idx = it * NTH + tid;              // cell id in [0, 3200)
        if (idx < 3200) {
            int cb  = idx / NPIX;
            int pix = idx - cb * NPIX;
            const float* s = xsrc + (size_t)(cb * 8) * NPIX + pix;
            __half2 h0 = __floats2half2_rn(s[0 * NPIX], s[1 * NPIX]);
            __half2 h1 = __floats2half2_rn(s[2 * NPIX], s[3 * NPIX]);
            __half2 h2 = __floats2half2_rn(s[4 * NPIX], s[5 * NPIX]);
            __half2 h3 = __floats2half2_rn(s[6 * NPIX], s[7 * NPIX]);
            uint4 pk;
            pk.x = __builtin_bit_cast(uint32_t, h0);
            pk.y = __builtin_bit_cast(uint32_t, h1);
            pk.z = __builtin_bit_cast(uint32_t, h2);
            pk.w = __builtin_bit_cast(uint32_t, h3);
            *(uint4*)&xb[(size_t)idx * 8] = pk;
        }
    }

    // ---- warp tables: wave wv handles flow fi=wv, pixels p = it*64 + lane ----
    __half2 w2_[2][4];
    int     pb_[2][4];     // corner cell byte offset within cb-plane (pr*16)
    int     fo_[2];        // fl byte offset = p*144 + wv*16

    auto build_tables = [&](int fb) {
        #pragma unroll
        for (int it = 0; it < 2; ++it) {
            if (it == 0 || lane < 16) {
                int p  = it * 64 + lane;       // [0,80)
                int f  = fb * 8 + wv;
                int gp = p0 + p;
                int i = gp / WW;
                int j = gp - i * WW;
                float fx = flowg[((f * HH + i) * WW + j) * 2 + 0];
                float fy = flowg[((f * HH + i) * WW + j) * 2 + 1];
                float ax = (float)i + fx;
                float ay = (float)j + fy;
                float bxf = floorf(ax), byf = floorf(ay);
                float s = ax - bxf, t = ay - byf;
                int ibx = (int)bxf, iby = (int)byf;
                float w00 = (1.f - s) * (1.f - t);
                float w01 = s * (1.f - t);
                float w10 = s * (1.f - t);        // replicate reference's weight bug
                float w11 = s * t;
                int cx0 = min(max(ibx, 0), HH);
                int cx1 = min(max(ibx + 1, 0), HH);
                int cy0 = min(max(iby, 0), WW);
                int cy1 = min(max(iby + 1, 0), WW);
                int v0 = (cx0 < HH) & (cy0 < WW);
                int v1 = (cx1 < HH) & (cy0 < WW);
                int v2 = (cx0 < HH) & (cy1 < WW);
                int v3 = (cx1 < HH) & (cy1 < WW);
                w2_[it][0] = __half2half2(__float2half(v0 ? w00 : 0.f));
                w2_[it][1] = __half2half2(__float2half(v1 ? w01 : 0.f));
                w2_[it][2] = __half2half2(__float2half(v2 ? w10 : 0.f));
                w2_[it][3] = __half2half2(__float2half(v3 ? w11 : 0.f));
                pb_[it][0] = (v0 ? (cx0 * WW + cy0) : 0) * 16;
                pb_[it][1] = (v1 ? (cx1 * WW + cy0) : 0) * 16;
                pb_[it][2] = (v2 ? (cx0 * WW + cy1) : 0) * 16;
                pb_[it][3] = (v3 ? (cx1 * WW + cy1) : 0) * 16;
                fo_[it] = p * (FLS * 2) + wv * 16;
            }
        }
    };

    // ---- fill chunk kc: gather 8 channels (cb) of flow fi=wv into fl[kc&1] ----
    auto fill = [&](int kc) {
        const char* xcb = (const char*)xb + (kc & 7) * 6400;
        char* flb = (char*)fl[kc & 1];
        #pragma unroll
        for (int it = 0; it < 2; ++it) {
            if (it == 0 || lane < 16) {
                __half2 s0 = __builtin_bit_cast(__half2, 0u);
                __half2 s1 = s0, s2 = s0, s3 = s0;
                #pragma unroll
                for (int q = 0; q < 4; ++q) {
                    const uint4 d = *(const uint4*)(xcb + pb_[it][q]);
                    __half2 wq = w2_[it][q];
                    s0 = __hfma2(wq, __builtin_bit_cast(__half2, d.x), s0);
                    s1 = __hfma2(wq, __builtin_bit_cast(__half2, d.y), s1);
                    s2 = __hfma2(wq, __builtin_bit_cast(__half2, d.z), s2);
                    s3 = __hfma2(wq, __builtin_bit_cast(__half2, d.w), s3);
                }
                uint4 pk;
                pk.x = __builtin_bit_cast(uint32_t, s0);
                pk.y = __builtin_bit_cast(uint32_t, s1);
                pk.z = __builtin_bit_cast(uint32_t, s2);
                pk.w = __builtin_bit_cast(uint32_t, s3);
                *(uint4*)(flb + fo_[it]) = pk;
            }
        }
    };

    build_tables(0);
    __syncthreads();   // xb staged
    fill(0);
    __syncthreads();   // fl[0] ready

    f4 acc[2][5] = {};

    for (int kc = 0; kc < 16; ++kc) {          // chunk = (fb = kc>>3, cb = kc&7)
        if (kc == 7) build_tables(1);          // tables for fb=1 before fill(8)

        // ---- A-frags: 2 M-frags x 2 k-halves (L2-resident; fill covers latency) ----
        const sh8* wfp = (const sh8*)Wf + (size_t)(2 * kc * 16 + 2 * wv) * 64 + lane;
        sh8 a00 = wfp[0];          // kc16=2kc,   mf=2wv
        sh8 a01 = wfp[64];         // kc16=2kc,   mf=2wv+1
        sh8 a10 = wfp[1024];       // kc16=2kc+1, mf=2wv
        sh8 a11 = wfp[1088];       // kc16=2kc+1, mf=2wv+1

        // ---- pipelined fill of NEXT chunk (other buffer; hazard cleared by
        //      the barrier at the end of the previous iteration) ----
        if (kc < 15) fill(kc + 1);

        // ---- MFMA on current chunk: 20 x 16x16x32_f16 per wave ----
        const __half* flr = fl[kc & 1];
        __builtin_amdgcn_s_setprio(1);
        #pragma unroll
        for (int nf = 0; nf < 5; ++nf) {
            sh8 b0 = *(const sh8*)&flr[(nf * 16 + lr) * FLS + lk];
            acc[0][nf] = __builtin_amdgcn_mfma_f32_16x16x32_f16(a00, b0, acc[0][nf], 0, 0, 0);
            acc[1][nf] = __builtin_amdgcn_mfma_f32_16x16x32_f16(a01, b0, acc[1][nf], 0, 0, 0);
            sh8 b1 = *(const sh8*)&flr[(nf * 16 + lr) * FLS + 32 + lk];
            acc[0][nf] = __builtin_amdgcn_mfma_f32_16x16x32_f16(a10, b1, acc[0][nf], 0, 0, 0);
            acc[1][nf] = __builtin_amdgcn_mfma_f32_16x16x32_f16(a11, b1, acc[1][nf], 0, 0, 0);
        }
        __builtin_amdgcn_s_setprio(0);

        __syncthreads();   // fl[(kc+1)&1] complete for all waves (sole barrier)
    }

    // ---- epilogue: bias + fp32 store ----
    float* ob = outg + (size_t)b * (COUT * NPIX) + p0;
    #pragma unroll
    for (int mi = 0; mi < 2; ++mi) {
        #pragma unroll
        for (int r = 0; r < 4; ++r) {
            int m = (wv * 2 + mi) * 16 + (lane >> 4) * 4 + r;
            float bs = biasg[m];
            #pragma unroll
            for (int nf = 0; nf < 5; ++nf)
                ob[(size_t)m * NPIX + nf * 16 + lr] = acc[mi][nf][r] + bs;
        }
    }
}

extern "C" void kernel_launch(void* const* d_in, const int* in_sizes, int n_in,
                              void* d_out, int out_size, void* d_ws, size_t ws_size,
                              hipStream_t stream) {
    const float* x    = (const float*)d_in[0];
    const float* flow = (const float*)d_in[1];
    const float* comb = (const float*)d_in[2];
    const float* bias = (const float*)d_in[3];
    float* out = (float*)d_out;

    __half* Wf = (__half*)d_ws;   // 512 KB frag-layout f16 W

    prep_w<<<dim3(128), dim3(256), 0, stream>>>(comb, Wf);
    flow_main<<<dim3(BATCH * NPT), dim3(NTH), 0, stream>>>(x, Wf, flow, bias, out);
}